// Round 1
// baseline (10557.938 us; speedup 1.0000x reference)
//
#include <hip/hip_runtime.h>
#include <math.h>

// ============================================================================
// CapsuleNet forward, fp32 baseline (round 1).
// Stages: conv1+relu -> primary conv (implicit GEMM) -> squash -> priors+routing
//         (priors kept in registers, one block per (class,batch)) -> classes/
//         argmax/mask -> 3-layer decoder MLP.
// ws layout: h[209.7MB] | u_pre[18.9MB] | u[18.9MB]; caps/d0/d1/d2 alias the
// (dead-by-then) h region. Total ws needed ~247.5 MB.
// ============================================================================

// ---------------- conv1: x[512,1,28,28] -> h[512,256,20,20], relu ----------
__global__ __launch_bounds__(256, 2) void conv1_kernel(
    const float* __restrict__ x, const float* __restrict__ w,
    const float* __restrict__ bias, float* __restrict__ h)
{
  __shared__ float xs[784];
  const int b = blockIdx.x;
  const int t = threadIdx.x;          // t == output channel
  for (int i = t; i < 784; i += 256) xs[i] = x[b * 784 + i];
  float wr[81];
#pragma unroll
  for (int k = 0; k < 81; ++k) wr[k] = w[t * 81 + k];
  const float bv = bias[t];
  __syncthreads();
  for (int oy = 0; oy < 20; ++oy) {
    float acc[20];
#pragma unroll
    for (int i = 0; i < 20; ++i) acc[i] = bv;
#pragma unroll
    for (int ky = 0; ky < 9; ++ky) {
      float xr[28];
#pragma unroll
      for (int q = 0; q < 7; ++q) {   // row base is 112B (16B-aligned), bcast
        const float4 v = *(const float4*)&xs[(oy + ky) * 28 + q * 4];
        xr[q*4+0] = v.x; xr[q*4+1] = v.y; xr[q*4+2] = v.z; xr[q*4+3] = v.w;
      }
#pragma unroll
      for (int kx = 0; kx < 9; ++kx) {
        const float wv = wr[ky * 9 + kx];
#pragma unroll
        for (int ox = 0; ox < 20; ++ox) acc[ox] = fmaf(xr[ox + kx], wv, acc[ox]);
      }
    }
    float* hp = &h[(b * 256 + t) * 400 + oy * 20];
#pragma unroll
    for (int q = 0; q < 5; ++q) {
      float4 o;
      o.x = fmaxf(acc[q*4+0], 0.f); o.y = fmaxf(acc[q*4+1], 0.f);
      o.z = fmaxf(acc[q*4+2], 0.f); o.w = fmaxf(acc[q*4+3], 0.f);
      *(float4*)&hp[q * 4] = o;
    }
  }
}

// ------------- primary caps conv: implicit GEMM --------------------------
// M=18432 rows (b,pos), N=256 oc, K=256*81. BM=144 (4 imgs), BN=128, BK=27+1.
// 256 thr: tm=t>>4 -> rows tm*9..+8 ; tn=t&15 -> cols {tn+16n} (strided to
// keep LDS W-fragment reads at free 2-way bank aliasing).
__global__ __launch_bounds__(256, 1) void prim_conv_kernel(
    const float* __restrict__ h, const float* __restrict__ w,
    const float* __restrict__ bias, float* __restrict__ u_pre)
{
  __shared__ float As[144 * 28];
  __shared__ float Ws[128 * 28];
  const int t = threadIdx.x;
  const int tm = t >> 4;
  const int tn = t & 15;
  const int b0 = blockIdx.x * 4;
  const int oc0 = blockIdx.y * 128;

  // Precompute im2col gather bases for this thread's staging slots.
  // A slot ii: idx = t + 256*ii  (144*28 = 4032 -> 16 slots, last partial)
  int abase[16]; bool avalid[16];
#pragma unroll
  for (int ii = 0; ii < 16; ++ii) {
    const int idx = t + 256 * ii;
    if (idx < 144 * 28) {
      const int row = idx / 28, col = idx - row * 28;
      if (col < 27) {
        const int img = row / 36, pos = row - img * 36;
        const int oy = pos / 6, ox = pos - oy * 6;
        const int kyl = col / 9, kx = col - kyl * 9;
        abase[ii] = (b0 + img) * 102400 + (2 * oy + kyl) * 20 + (2 * ox + kx);
        avalid[ii] = true;
      } else { abase[ii] = 0; avalid[ii] = false; }
    } else { abase[ii] = 0; avalid[ii] = false; }
  }
  // W slot ii: idx = t + 256*ii (128*28 = 3584 -> 14 slots exact)
  int wbase[14]; bool wvalid[14];
#pragma unroll
  for (int ii = 0; ii < 14; ++ii) {
    const int idx = t + 256 * ii;
    const int row = idx / 28, col = idx - row * 28;
    wbase[ii] = (oc0 + row) * 20736 + col;
    wvalid[ii] = (col < 27);
  }

  float acc[9][8] = {};

  for (int ic = 0; ic < 256; ++ic) {
    for (int j = 0; j < 3; ++j) {
      __syncthreads();
#pragma unroll
      for (int ii = 0; ii < 16; ++ii) {
        const int idx = t + 256 * ii;
        if (idx < 144 * 28)
          As[idx] = avalid[ii] ? h[abase[ii] + ic * 400 + 60 * j] : 0.f;
      }
#pragma unroll
      for (int ii = 0; ii < 14; ++ii) {
        const int idx = t + 256 * ii;
        Ws[idx] = wvalid[ii] ? w[wbase[ii] + ic * 81 + 27 * j] : 0.f;
      }
      __syncthreads();
      for (int k = 0; k < 28; k += 4) {
        float4 a4[9], w4[8];
#pragma unroll
        for (int i = 0; i < 9; ++i)
          a4[i] = *(const float4*)&As[(tm * 9 + i) * 28 + k];
#pragma unroll
        for (int n = 0; n < 8; ++n)
          w4[n] = *(const float4*)&Ws[(tn + 16 * n) * 28 + k];
#pragma unroll
        for (int i = 0; i < 9; ++i)
#pragma unroll
          for (int n = 0; n < 8; ++n) {
            acc[i][n] = fmaf(a4[i].x, w4[n].x, acc[i][n]);
            acc[i][n] = fmaf(a4[i].y, w4[n].y, acc[i][n]);
            acc[i][n] = fmaf(a4[i].z, w4[n].z, acc[i][n]);
            acc[i][n] = fmaf(a4[i].w, w4[n].w, acc[i][n]);
          }
      }
    }
  }
#pragma unroll
  for (int i = 0; i < 9; ++i) {
    const int row = tm * 9 + i;
    const int img = row / 36;
    const int pos = row - img * 36;
    const int b = b0 + img;
#pragma unroll
    for (int n = 0; n < 8; ++n) {
      const int oc = oc0 + tn + 16 * n;
      u_pre[(b * 256 + oc) * 36 + pos] = acc[i][n] + bias[oc];
    }
  }
}

// ---------------- squash u_pre[512,256,36] -> u[512,1152,8] ----------------
__global__ void squash_kernel(const float* __restrict__ u_pre, float* __restrict__ u)
{
  const int tid = blockIdx.x * 256 + threadIdx.x;   // b*1152 + r
  if (tid >= 512 * 1152) return;
  const int b = tid / 1152;
  const int r = tid - b * 1152;
  const int cc = r / 36;
  const int pos = r - cc * 36;
  float v[8];
  float sq = 0.f;
#pragma unroll
  for (int i = 0; i < 8; ++i) {
    v[i] = u_pre[(b * 256 + i * 32 + cc) * 36 + pos];
    sq = fmaf(v[i], v[i], sq);
  }
  const float scale = sq / ((1.f + sq) * sqrtf(sq));
  float* up = &u[tid * 8];
#pragma unroll
  for (int i = 0; i < 8; ++i) up[i] = v[i] * scale;
}

// ---------------- priors + dynamic routing, one block per (c,b) ------------
__device__ __forceinline__ float wave_sum(float v) {
#pragma unroll
  for (int off = 32; off > 0; off >>= 1) v += __shfl_xor(v, off);
  return v;
}
__device__ __forceinline__ float wave_max(float v) {
#pragma unroll
  for (int off = 32; off > 0; off >>= 1) v = fmaxf(v, __shfl_xor(v, off));
  return v;
}

__global__ __launch_bounds__(256, 2) void routing_kernel(
    const float* __restrict__ u, const float* __restrict__ rw,
    float* __restrict__ caps)
{
  const int c = blockIdx.x >> 9;
  const int b = blockIdx.x & 511;
  const int t = threadIdx.x;
  const int wid = t >> 6;
  const int lane = t & 63;
  __shared__ float xred[4 * 17];

  // priors for this thread's rows r = t + 256k, k<nk, held in registers.
  float P[5][16];
  float lg[5];
  const int nk = (t < 128) ? 5 : 4;
#pragma unroll
  for (int k = 0; k < 5; ++k)
#pragma unroll
    for (int o = 0; o < 16; ++o) P[k][o] = 0.f;

#pragma unroll
  for (int k = 0; k < 5; ++k) {
    if (k < nk) {
      const int r = t + (k << 8);
      const float4 ua = *(const float4*)&u[(b * 1152 + r) * 8];
      const float4 ub = *(const float4*)&u[(b * 1152 + r) * 8 + 4];
      const float uu[8] = {ua.x, ua.y, ua.z, ua.w, ub.x, ub.y, ub.z, ub.w};
      const float4* wp = (const float4*)&rw[(size_t)((c * 1152 + r) * 8) * 16];
#pragma unroll
      for (int i = 0; i < 8; ++i) {
        const float ui = uu[i];
#pragma unroll
        for (int og = 0; og < 4; ++og) {
          const float4 w4 = wp[i * 4 + og];
          P[k][og*4+0] = fmaf(ui, w4.x, P[k][og*4+0]);
          P[k][og*4+1] = fmaf(ui, w4.y, P[k][og*4+1]);
          P[k][og*4+2] = fmaf(ui, w4.z, P[k][og*4+2]);
          P[k][og*4+3] = fmaf(ui, w4.w, P[k][og*4+3]);
        }
      }
    }
  }

  float v[16];
  // ---- iteration 0: uniform probs (softmax of zeros) ----
  {
    float sq = 0.f;
#pragma unroll
    for (int o = 0; o < 16; ++o) {
      float p = 0.f;
#pragma unroll
      for (int k = 0; k < 5; ++k) p += P[k][o];   // invalid P[4] stays 0
      p = wave_sum(p);
      if (lane == 0) xred[wid * 17 + o] = p;
      v[o] = 0.f;
    }
    __syncthreads();
#pragma unroll
    for (int o = 0; o < 16; ++o) {
      const float s = (xred[o] + xred[17 + o] + xred[34 + o] + xred[51 + o]) *
                      (1.f / 1152.f);
      v[o] = s;
      sq = fmaf(s, s, sq);
    }
    const float scale = sq / ((1.f + sq) * sqrtf(sq));
#pragma unroll
    for (int o = 0; o < 16; ++o) v[o] *= scale;
    __syncthreads();
  }
  // logits after iter 0 (logits started at zero)
#pragma unroll
  for (int k = 0; k < 5; ++k) {
    float a = 0.f;
#pragma unroll
    for (int o = 0; o < 16; ++o) a = fmaf(P[k][o], v[o], a);
    lg[k] = a;
  }

  for (int it = 1; it < 3; ++it) {
    // softmax max over r
    float m = -1e30f;
#pragma unroll
    for (int k = 0; k < 5; ++k) if (k < nk) m = fmaxf(m, lg[k]);
    m = wave_max(m);
    if (lane == 0) xred[wid * 17 + 16] = m;
    __syncthreads();
    const float mx = fmaxf(fmaxf(xred[16], xred[17 + 16]),
                           fmaxf(xred[34 + 16], xred[51 + 16]));
    __syncthreads();
    float e[5];
#pragma unroll
    for (int k = 0; k < 5; ++k) e[k] = (k < nk) ? expf(lg[k] - mx) : 0.f;
    float pS = 0.f;
#pragma unroll
    for (int k = 0; k < 5; ++k) pS += e[k];
    pS = wave_sum(pS);
    if (lane == 0) xred[wid * 17 + 16] = pS;
#pragma unroll
    for (int o = 0; o < 16; ++o) {
      float p = 0.f;
#pragma unroll
      for (int k = 0; k < 5; ++k) p = fmaf(e[k], P[k][o], p);
      p = wave_sum(p);
      if (lane == 0) xred[wid * 17 + o] = p;
    }
    __syncthreads();
    const float S = xred[16] + xred[17 + 16] + xred[34 + 16] + xred[51 + 16];
    const float inv = 1.f / S;
    float sq = 0.f;
#pragma unroll
    for (int o = 0; o < 16; ++o) {
      const float s = (xred[o] + xred[17 + o] + xred[34 + o] + xred[51 + o]) * inv;
      v[o] = s;
      sq = fmaf(s, s, sq);
    }
    const float scale = sq / ((1.f + sq) * sqrtf(sq));
#pragma unroll
    for (int o = 0; o < 16; ++o) v[o] *= scale;
    __syncthreads();
    if (it < 2) {
#pragma unroll
      for (int k = 0; k < 5; ++k) {
        float a = 0.f;
#pragma unroll
        for (int o = 0; o < 16; ++o) a = fmaf(P[k][o], v[o], a);
        lg[k] += a;
      }
    }
  }
  if (t == 0) {
    float* cp = &caps[(b * 10 + c) * 16];
#pragma unroll
    for (int o = 0; o < 16; ++o) cp[o] = v[o];
  }
}

// --------- classes softmax + argmax one-hot mask, thread per batch ---------
__global__ void classes_kernel(const float* __restrict__ caps,
                               float* __restrict__ out_classes,
                               float* __restrict__ d0)
{
  const int b = blockIdx.x * 256 + threadIdx.x;
  if (b >= 512) return;
  float nrm[10];
#pragma unroll
  for (int cc = 0; cc < 10; ++cc) {
    float sq = 0.f;
#pragma unroll
    for (int o = 0; o < 16; ++o) {
      const float vv = caps[(b * 10 + cc) * 16 + o];
      sq = fmaf(vv, vv, sq);
    }
    nrm[cc] = sqrtf(sq);
  }
  float mx = nrm[0]; int cs = 0;
#pragma unroll
  for (int cc = 1; cc < 10; ++cc)
    if (nrm[cc] > mx) { mx = nrm[cc]; cs = cc; }   // strict > == first argmax
  float e[10], ssum = 0.f;
#pragma unroll
  for (int cc = 0; cc < 10; ++cc) { e[cc] = expf(nrm[cc] - mx); ssum += e[cc]; }
  const float inv = 1.f / ssum;
#pragma unroll
  for (int cc = 0; cc < 10; ++cc) out_classes[b * 10 + cc] = e[cc] * inv;
#pragma unroll
  for (int cc = 0; cc < 10; ++cc)
#pragma unroll
    for (int o = 0; o < 16; ++o)
      d0[b * 160 + cc * 16 + o] = (cc == cs) ? caps[(b * 10 + cc) * 16 + o] : 0.f;
}

// --------- decoder GEMM: C[M,N] = act(A[M,K] @ W[N,K]^T + bias) ------------
__global__ __launch_bounds__(256, 2) void fc_kernel(
    const float* __restrict__ A, const float* __restrict__ W,
    const float* __restrict__ bias, float* __restrict__ C,
    int N, int K, int act)
{
  __shared__ float As[64][17];
  __shared__ float Ws[64][17];
  const int t = threadIdx.x;
  const int tm = t >> 4, tn = t & 15;
  const int m0 = blockIdx.y << 6, n0 = blockIdx.x << 6;
  const int lr = t >> 2, lq = (t & 3) << 2;
  float acc[4][4] = {};
  for (int k0 = 0; k0 < K; k0 += 16) {
    const float4 av = *(const float4*)&A[(m0 + lr) * K + k0 + lq];
    float4 wv = make_float4(0.f, 0.f, 0.f, 0.f);
    const int wn = n0 + lr;
    if (wn < N) wv = *(const float4*)&W[wn * K + k0 + lq];
    __syncthreads();
    As[lr][lq+0] = av.x; As[lr][lq+1] = av.y; As[lr][lq+2] = av.z; As[lr][lq+3] = av.w;
    Ws[lr][lq+0] = wv.x; Ws[lr][lq+1] = wv.y; Ws[lr][lq+2] = wv.z; Ws[lr][lq+3] = wv.w;
    __syncthreads();
#pragma unroll
    for (int kk = 0; kk < 16; ++kk) {
      float a[4], w[4];
#pragma unroll
      for (int i = 0; i < 4; ++i) a[i] = As[tm * 4 + i][kk];
#pragma unroll
      for (int j = 0; j < 4; ++j) w[j] = Ws[tn * 4 + j][kk];
#pragma unroll
      for (int i = 0; i < 4; ++i)
#pragma unroll
        for (int j = 0; j < 4; ++j) acc[i][j] = fmaf(a[i], w[j], acc[i][j]);
    }
  }
#pragma unroll
  for (int i = 0; i < 4; ++i) {
    const int m = m0 + tm * 4 + i;
#pragma unroll
    for (int j = 0; j < 4; ++j) {
      const int n = n0 + tn * 4 + j;
      if (n < N) {
        float vv = acc[i][j] + bias[n];
        vv = act ? (1.f / (1.f + expf(-vv))) : fmaxf(vv, 0.f);
        C[m * N + n] = vv;
      }
    }
  }
}

// ============================================================================
extern "C" void kernel_launch(void* const* d_in, const int* in_sizes, int n_in,
                              void* d_out, int out_size, void* d_ws, size_t ws_size,
                              hipStream_t stream)
{
  const float* x       = (const float*)d_in[0];
  const float* conv1_w = (const float*)d_in[1];
  const float* conv1_b = (const float*)d_in[2];
  const float* prim_w  = (const float*)d_in[3];
  const float* prim_b  = (const float*)d_in[4];
  const float* route_w = (const float*)d_in[5];
  const float* dec_w1  = (const float*)d_in[6];
  const float* dec_b1  = (const float*)d_in[7];
  const float* dec_w2  = (const float*)d_in[8];
  const float* dec_b2  = (const float*)d_in[9];
  const float* dec_w3  = (const float*)d_in[10];
  const float* dec_b3  = (const float*)d_in[11];
  float* out = (float*)d_out;

  char* ws = (char*)d_ws;
  float* h     = (float*)(ws);                               // 209,715,200 B
  float* u_pre = (float*)(ws + 209715200);                   //  18,874,368 B
  float* u     = (float*)(ws + 209715200 + 18874368);        //  18,874,368 B
  // h is dead after prim_conv: reuse its region for the small tail tensors.
  float* caps  = (float*)(ws);                               // 327,680 B
  float* d0    = (float*)(ws + 327680);                      // 327,680 B
  float* d1    = (float*)(ws + 655360);                      // 1,048,576 B
  float* d2    = (float*)(ws + 1703936);                     // 2,097,152 B

  hipLaunchKernelGGL(conv1_kernel, dim3(512), dim3(256), 0, stream,
                     x, conv1_w, conv1_b, h);
  hipLaunchKernelGGL(prim_conv_kernel, dim3(128, 2), dim3(256), 0, stream,
                     h, prim_w, prim_b, u_pre);
  hipLaunchKernelGGL(squash_kernel, dim3(2304), dim3(256), 0, stream, u_pre, u);
  hipLaunchKernelGGL(routing_kernel, dim3(5120), dim3(256), 0, stream,
                     u, route_w, caps);
  hipLaunchKernelGGL(classes_kernel, dim3(2), dim3(256), 0, stream,
                     caps, out, d0);
  hipLaunchKernelGGL(fc_kernel, dim3(8, 8), dim3(256), 0, stream,
                     d0, dec_w1, dec_b1, d1, 512, 160, 0);
  hipLaunchKernelGGL(fc_kernel, dim3(16, 8), dim3(256), 0, stream,
                     d1, dec_w2, dec_b2, d2, 1024, 512, 0);
  hipLaunchKernelGGL(fc_kernel, dim3(13, 8), dim3(256), 0, stream,
                     d2, dec_w3, dec_b3, out + 5120, 784, 1024, 1);
}

// Round 2
// 2630.068 us; speedup vs baseline: 4.0143x; 4.0143x over previous
//
#include <hip/hip_runtime.h>
#include <math.h>

// ============================================================================
// CapsuleNet forward, round 2: primary-caps conv as fp16 MFMA implicit GEMM.
// conv1 -> h fp16 NHWC [b,y,x,ic]; wtrans -> wt fp16 [oc][kykx][ic];
// prim GEMM: M=18432 (b,pos), N=256 (oc), K=81*256, 128x128 tile, split-K 2,
// 16x16x32_f16 MFMA, global_load_lds(16B) staging (m97 structure);
// squash fuses split-K reduce + bias; routing/classes/decoder as round 1.
// ============================================================================

typedef _Float16 f16;
typedef _Float16 f16x8 __attribute__((ext_vector_type(8)));
typedef float f32x4 __attribute__((ext_vector_type(4)));

__device__ __forceinline__ void gl_lds16(const void* g, void* l) {
  __builtin_amdgcn_global_load_lds(
      (const __attribute__((address_space(1))) void*)g,
      (__attribute__((address_space(3))) void*)l, 16, 0, 0);
}

// ---------------- conv1: x[512,1,28,28] -> ht fp16 NHWC [512,20,20,256] ----
__global__ __launch_bounds__(256, 2) void conv1_kernel(
    const float* __restrict__ x, const float* __restrict__ w,
    const float* __restrict__ bias, f16* __restrict__ ht)
{
  __shared__ float xs[784];
  const int b = blockIdx.x;
  const int t = threadIdx.x;          // t == output channel (ic of ht)
  for (int i = t; i < 784; i += 256) xs[i] = x[b * 784 + i];
  float wr[81];
#pragma unroll
  for (int k = 0; k < 81; ++k) wr[k] = w[t * 81 + k];
  const float bv = bias[t];
  __syncthreads();
  for (int oy = 0; oy < 20; ++oy) {
    float acc[20];
#pragma unroll
    for (int i = 0; i < 20; ++i) acc[i] = bv;
#pragma unroll
    for (int ky = 0; ky < 9; ++ky) {
      float xr[28];
#pragma unroll
      for (int q = 0; q < 7; ++q) {
        const float4 v = *(const float4*)&xs[(oy + ky) * 28 + q * 4];
        xr[q*4+0] = v.x; xr[q*4+1] = v.y; xr[q*4+2] = v.z; xr[q*4+3] = v.w;
      }
#pragma unroll
      for (int kx = 0; kx < 9; ++kx) {
        const float wv = wr[ky * 9 + kx];
#pragma unroll
        for (int ox = 0; ox < 20; ++ox) acc[ox] = fmaf(xr[ox + kx], wv, acc[ox]);
      }
    }
    f16* hp = &ht[(size_t)((b * 20 + oy) * 20) * 256 + t];
#pragma unroll
    for (int ox = 0; ox < 20; ++ox)
      hp[ox * 256] = (f16)fmaxf(acc[ox], 0.f);
  }
}

// --------- weight transpose: prim_w fp32 [oc][ic][kykx] -> wt fp16 [oc][kykx][ic]
__global__ void wtrans_kernel(const float* __restrict__ w, f16* __restrict__ wt)
{
  const int tid = blockIdx.x * 256 + threadIdx.x;   // ((oc*81+kykx)<<8)|ic
  const int ic = tid & 255;
  const int rest = tid >> 8;                        // oc*81 + kykx
  const int oc = rest / 81;
  const int kykx = rest - oc * 81;
  wt[tid] = (f16)w[oc * 20736 + ic * 81 + kykx];
}

// ---------------- primary caps conv: MFMA implicit GEMM --------------------
// 576 blocks = 144 mb x 2 nb x 2 ksplit, XCD-swizzled so same-mb blocks share
// an XCD L2. 256 thr = 4 waves, wave tile 64x64 (4x4 of 16x16x32 MFMA).
__global__ __launch_bounds__(256) void prim_mfma_kernel(
    const f16* __restrict__ ht, const f16* __restrict__ wt,
    float* __restrict__ part)
{
  __shared__ f16 smem[8192];           // As[128][32] | Bs[128][32], 16 KB
  f16* As = smem;
  f16* Bs = smem + 4096;
  const int t = threadIdx.x;
  const int wv = t >> 6, lane = t & 63;
  // swizzle: id%8 == mb%8 -> the 4 (nb,ks) siblings of an mb land on one XCD
  const int id = blockIdx.x;
  const int g = id >> 3;
  const int mb = (id & 7) + 8 * (g >> 2);
  const int nb = (g >> 1) & 1;
  const int ks = g & 1;
  const int m0 = mb * 128, n0 = nb * 128;

  // staging: tile = 512 chunks of 16B; lane stages chunks wv*128 + {0,64} + lane
  long aoff[2], boff[2];
#pragma unroll
  for (int i = 0; i < 2; ++i) {
    const int c = wv * 128 + i * 64 + lane;
    const int r = c >> 2, o16 = c & 3;
    const int m = m0 + r;
    const int b = m / 36, pos = m - b * 36;
    const int oy = pos / 6, ox = pos - oy * 6;
    aoff[i] = (long)(((b * 20 + 2 * oy) * 20 + 2 * ox) * 256) * 2 + o16 * 16;
    const int oc = n0 + r;
    boff[i] = (long)oc * 41472 + o16 * 16;   // oc*81*256*2
  }
  char* As0 = (char*)As + wv * 2048;
  char* Bs0 = (char*)Bs + wv * 2048;
  const char* htc = (const char*)ht;
  const char* wtc = (const char*)wt;

  const int lrow = lane & 15, quad = lane >> 4;
  const int wm = wv & 1, wn = wv >> 1;
  f32x4 acc[4][4] = {};

  for (int s = ks * 324, e = ks * 324 + 324; s < e; ++s) {
    const int kykx = s >> 3, icb = s & 7;
    const int ky = kykx / 9, kx = kykx - ky * 9;
    const long astep = (long)(((ky * 20 + kx) * 256 + icb * 32) * 2);
    const long bstep = (long)((kykx * 256 + icb * 32) * 2);
    __syncthreads();
    gl_lds16(htc + aoff[0] + astep, As0);
    gl_lds16(htc + aoff[1] + astep, As0 + 1024);
    gl_lds16(wtc + boff[0] + bstep, Bs0);
    gl_lds16(wtc + boff[1] + bstep, Bs0 + 1024);
    __syncthreads();
    f16x8 af[4], bf[4];
#pragma unroll
    for (int mt = 0; mt < 4; ++mt)
      af[mt] = *(const f16x8*)&As[(wm * 64 + mt * 16 + lrow) * 32 + quad * 8];
#pragma unroll
    for (int nt = 0; nt < 4; ++nt)
      bf[nt] = *(const f16x8*)&Bs[(wn * 64 + nt * 16 + lrow) * 32 + quad * 8];
#pragma unroll
    for (int mt = 0; mt < 4; ++mt)
#pragma unroll
      for (int nt = 0; nt < 4; ++nt)
        acc[mt][nt] = __builtin_amdgcn_mfma_f32_16x16x32_f16(
            af[mt], bf[nt], acc[mt][nt], 0, 0, 0);
  }

  // epilogue: partials, m-major [m][oc]
  float* pp = part + (size_t)ks * 4718592;
#pragma unroll
  for (int mt = 0; mt < 4; ++mt) {
    const int mbase = m0 + wm * 64 + mt * 16 + quad * 4;  // C/D: row=quad*4+reg
#pragma unroll
    for (int nt = 0; nt < 4; ++nt) {
      const int n = n0 + wn * 64 + nt * 16 + lrow;        // col=lane&15
#pragma unroll
      for (int rg = 0; rg < 4; ++rg)
        pp[(size_t)(mbase + rg) * 256 + n] = acc[mt][nt][rg];
    }
  }
}

// --------- split-K reduce + bias + squash -> u[512,1152,8] -----------------
__global__ void squash_kernel(const float* __restrict__ part,
                              const float* __restrict__ bias,
                              float* __restrict__ u)
{
  const int tid = blockIdx.x * 256 + threadIdx.x;   // b*1152 + r
  if (tid >= 512 * 1152) return;
  const int b = tid / 1152;
  const int r = tid - b * 1152;
  const int cc = r / 36;
  const int pos = r - cc * 36;
  const float* p0 = part + (size_t)(b * 36 + pos) * 256;
  const float* p1 = p0 + 4718592;
  float v[8];
  float sq = 0.f;
#pragma unroll
  for (int i = 0; i < 8; ++i) {
    const int oc = i * 32 + cc;
    const float val = p0[oc] + p1[oc] + bias[oc];
    v[i] = val;
    sq = fmaf(val, val, sq);
  }
  const float scale = sq / ((1.f + sq) * sqrtf(sq));
  float* up = &u[(size_t)tid * 8];
#pragma unroll
  for (int i = 0; i < 8; ++i) up[i] = v[i] * scale;
}

// ---------------- priors + dynamic routing, one block per (c,b) ------------
__device__ __forceinline__ float wave_sum(float v) {
#pragma unroll
  for (int off = 32; off > 0; off >>= 1) v += __shfl_xor(v, off);
  return v;
}
__device__ __forceinline__ float wave_max(float v) {
#pragma unroll
  for (int off = 32; off > 0; off >>= 1) v = fmaxf(v, __shfl_xor(v, off));
  return v;
}

__global__ __launch_bounds__(256, 2) void routing_kernel(
    const float* __restrict__ u, const float* __restrict__ rw,
    float* __restrict__ caps)
{
  const int c = blockIdx.x >> 9;
  const int b = blockIdx.x & 511;
  const int t = threadIdx.x;
  const int wid = t >> 6;
  const int lane = t & 63;
  __shared__ float xred[4 * 17];

  float P[5][16];
  float lg[5];
  const int nk = (t < 128) ? 5 : 4;
#pragma unroll
  for (int k = 0; k < 5; ++k)
#pragma unroll
    for (int o = 0; o < 16; ++o) P[k][o] = 0.f;

#pragma unroll
  for (int k = 0; k < 5; ++k) {
    if (k < nk) {
      const int r = t + (k << 8);
      const float4 ua = *(const float4*)&u[(b * 1152 + r) * 8];
      const float4 ub = *(const float4*)&u[(b * 1152 + r) * 8 + 4];
      const float uu[8] = {ua.x, ua.y, ua.z, ua.w, ub.x, ub.y, ub.z, ub.w};
      const float4* wp = (const float4*)&rw[(size_t)((c * 1152 + r) * 8) * 16];
#pragma unroll
      for (int i = 0; i < 8; ++i) {
        const float ui = uu[i];
#pragma unroll
        for (int og = 0; og < 4; ++og) {
          const float4 w4 = wp[i * 4 + og];
          P[k][og*4+0] = fmaf(ui, w4.x, P[k][og*4+0]);
          P[k][og*4+1] = fmaf(ui, w4.y, P[k][og*4+1]);
          P[k][og*4+2] = fmaf(ui, w4.z, P[k][og*4+2]);
          P[k][og*4+3] = fmaf(ui, w4.w, P[k][og*4+3]);
        }
      }
    }
  }

  float v[16];
  {
    float sq = 0.f;
#pragma unroll
    for (int o = 0; o < 16; ++o) {
      float p = 0.f;
#pragma unroll
      for (int k = 0; k < 5; ++k) p += P[k][o];
      p = wave_sum(p);
      if (lane == 0) xred[wid * 17 + o] = p;
      v[o] = 0.f;
    }
    __syncthreads();
#pragma unroll
    for (int o = 0; o < 16; ++o) {
      const float s = (xred[o] + xred[17 + o] + xred[34 + o] + xred[51 + o]) *
                      (1.f / 1152.f);
      v[o] = s;
      sq = fmaf(s, s, sq);
    }
    const float scale = sq / ((1.f + sq) * sqrtf(sq));
#pragma unroll
    for (int o = 0; o < 16; ++o) v[o] *= scale;
    __syncthreads();
  }
#pragma unroll
  for (int k = 0; k < 5; ++k) {
    float a = 0.f;
#pragma unroll
    for (int o = 0; o < 16; ++o) a = fmaf(P[k][o], v[o], a);
    lg[k] = a;
  }

  for (int it = 1; it < 3; ++it) {
    float m = -1e30f;
#pragma unroll
    for (int k = 0; k < 5; ++k) if (k < nk) m = fmaxf(m, lg[k]);
    m = wave_max(m);
    if (lane == 0) xred[wid * 17 + 16] = m;
    __syncthreads();
    const float mx = fmaxf(fmaxf(xred[16], xred[17 + 16]),
                           fmaxf(xred[34 + 16], xred[51 + 16]));
    __syncthreads();
    float e[5];
#pragma unroll
    for (int k = 0; k < 5; ++k) e[k] = (k < nk) ? expf(lg[k] - mx) : 0.f;
    float pS = 0.f;
#pragma unroll
    for (int k = 0; k < 5; ++k) pS += e[k];
    pS = wave_sum(pS);
    if (lane == 0) xred[wid * 17 + 16] = pS;
#pragma unroll
    for (int o = 0; o < 16; ++o) {
      float p = 0.f;
#pragma unroll
      for (int k = 0; k < 5; ++k) p = fmaf(e[k], P[k][o], p);
      p = wave_sum(p);
      if (lane == 0) xred[wid * 17 + o] = p;
    }
    __syncthreads();
    const float S = xred[16] + xred[17 + 16] + xred[34 + 16] + xred[51 + 16];
    const float inv = 1.f / S;
    float sq = 0.f;
#pragma unroll
    for (int o = 0; o < 16; ++o) {
      const float s = (xred[o] + xred[17 + o] + xred[34 + o] + xred[51 + o]) * inv;
      v[o] = s;
      sq = fmaf(s, s, sq);
    }
    const float scale = sq / ((1.f + sq) * sqrtf(sq));
#pragma unroll
    for (int o = 0; o < 16; ++o) v[o] *= scale;
    __syncthreads();
    if (it < 2) {
#pragma unroll
      for (int k = 0; k < 5; ++k) {
        float a = 0.f;
#pragma unroll
        for (int o = 0; o < 16; ++o) a = fmaf(P[k][o], v[o], a);
        lg[k] += a;
      }
    }
  }
  if (t == 0) {
    float* cp = &caps[(b * 10 + c) * 16];
#pragma unroll
    for (int o = 0; o < 16; ++o) cp[o] = v[o];
  }
}

// --------- classes softmax + argmax one-hot mask ---------------------------
__global__ void classes_kernel(const float* __restrict__ caps,
                               float* __restrict__ out_classes,
                               float* __restrict__ d0)
{
  const int b = blockIdx.x * 256 + threadIdx.x;
  if (b >= 512) return;
  float nrm[10];
#pragma unroll
  for (int cc = 0; cc < 10; ++cc) {
    float sq = 0.f;
#pragma unroll
    for (int o = 0; o < 16; ++o) {
      const float vv = caps[(b * 10 + cc) * 16 + o];
      sq = fmaf(vv, vv, sq);
    }
    nrm[cc] = sqrtf(sq);
  }
  float mx = nrm[0]; int cs = 0;
#pragma unroll
  for (int cc = 1; cc < 10; ++cc)
    if (nrm[cc] > mx) { mx = nrm[cc]; cs = cc; }
  float e[10], ssum = 0.f;
#pragma unroll
  for (int cc = 0; cc < 10; ++cc) { e[cc] = expf(nrm[cc] - mx); ssum += e[cc]; }
  const float inv = 1.f / ssum;
#pragma unroll
  for (int cc = 0; cc < 10; ++cc) out_classes[b * 10 + cc] = e[cc] * inv;
#pragma unroll
  for (int cc = 0; cc < 10; ++cc)
#pragma unroll
    for (int o = 0; o < 16; ++o)
      d0[b * 160 + cc * 16 + o] = (cc == cs) ? caps[(b * 10 + cc) * 16 + o] : 0.f;
}

// --------- decoder GEMM: C[M,N] = act(A[M,K] @ W[N,K]^T + bias) ------------
__global__ __launch_bounds__(256, 2) void fc_kernel(
    const float* __restrict__ A, const float* __restrict__ W,
    const float* __restrict__ bias, float* __restrict__ C,
    int N, int K, int act)
{
  __shared__ float As[64][17];
  __shared__ float Ws[64][17];
  const int t = threadIdx.x;
  const int tm = t >> 4, tn = t & 15;
  const int m0 = blockIdx.y << 6, n0 = blockIdx.x << 6;
  const int lr = t >> 2, lq = (t & 3) << 2;
  float acc[4][4] = {};
  for (int k0 = 0; k0 < K; k0 += 16) {
    const float4 av = *(const float4*)&A[(m0 + lr) * K + k0 + lq];
    float4 wv = make_float4(0.f, 0.f, 0.f, 0.f);
    const int wn = n0 + lr;
    if (wn < N) wv = *(const float4*)&W[wn * K + k0 + lq];
    __syncthreads();
    As[lr][lq+0] = av.x; As[lr][lq+1] = av.y; As[lr][lq+2] = av.z; As[lr][lq+3] = av.w;
    Ws[lr][lq+0] = wv.x; Ws[lr][lq+1] = wv.y; Ws[lr][lq+2] = wv.z; Ws[lr][lq+3] = wv.w;
    __syncthreads();
#pragma unroll
    for (int kk = 0; kk < 16; ++kk) {
      float a[4], w[4];
#pragma unroll
      for (int i = 0; i < 4; ++i) a[i] = As[tm * 4 + i][kk];
#pragma unroll
      for (int j = 0; j < 4; ++j) w[j] = Ws[tn * 4 + j][kk];
#pragma unroll
      for (int i = 0; i < 4; ++i)
#pragma unroll
        for (int j = 0; j < 4; ++j) acc[i][j] = fmaf(a[i], w[j], acc[i][j]);
    }
  }
#pragma unroll
  for (int i = 0; i < 4; ++i) {
    const int m = m0 + tm * 4 + i;
#pragma unroll
    for (int j = 0; j < 4; ++j) {
      const int n = n0 + tn * 4 + j;
      if (n < N) {
        float vv = acc[i][j] + bias[n];
        vv = act ? (1.f / (1.f + expf(-vv))) : fmaxf(vv, 0.f);
        C[m * N + n] = vv;
      }
    }
  }
}

// ============================================================================
extern "C" void kernel_launch(void* const* d_in, const int* in_sizes, int n_in,
                              void* d_out, int out_size, void* d_ws, size_t ws_size,
                              hipStream_t stream)
{
  const float* x       = (const float*)d_in[0];
  const float* conv1_w = (const float*)d_in[1];
  const float* conv1_b = (const float*)d_in[2];
  const float* prim_w  = (const float*)d_in[3];
  const float* prim_b  = (const float*)d_in[4];
  const float* route_w = (const float*)d_in[5];
  const float* dec_w1  = (const float*)d_in[6];
  const float* dec_b1  = (const float*)d_in[7];
  const float* dec_w2  = (const float*)d_in[8];
  const float* dec_b2  = (const float*)d_in[9];
  const float* dec_w3  = (const float*)d_in[10];
  const float* dec_b3  = (const float*)d_in[11];
  float* out = (float*)d_out;

  char* ws = (char*)d_ws;
  f16*   ht   = (f16*)(ws);                        // 104,857,600 B
  f16*   wtp  = (f16*)(ws + 104857600);            //  10,616,832 B
  float* part = (float*)(ws + 115474432);          //  37,748,736 B (2 splits)
  float* u    = (float*)(ws + 153223168);          //  18,874,368 B
  // ht region is dead after prim_mfma: reuse for tail tensors.
  float* caps = (float*)(ws);                      // 327,680 B
  float* d0   = (float*)(ws + 327680);
  float* d1   = (float*)(ws + 655360);
  float* d2   = (float*)(ws + 1703936);

  hipLaunchKernelGGL(conv1_kernel, dim3(512), dim3(256), 0, stream,
                     x, conv1_w, conv1_b, ht);
  hipLaunchKernelGGL(wtrans_kernel, dim3(20736), dim3(256), 0, stream,
                     prim_w, wtp);
  hipLaunchKernelGGL(prim_mfma_kernel, dim3(576), dim3(256), 0, stream,
                     ht, wtp, part);
  hipLaunchKernelGGL(squash_kernel, dim3(2304), dim3(256), 0, stream,
                     part, prim_b, u);
  hipLaunchKernelGGL(routing_kernel, dim3(5120), dim3(256), 0, stream,
                     u, route_w, caps);
  hipLaunchKernelGGL(classes_kernel, dim3(2), dim3(256), 0, stream,
                     caps, out, d0);
  hipLaunchKernelGGL(fc_kernel, dim3(8, 8), dim3(256), 0, stream,
                     d0, dec_w1, dec_b1, d1, 512, 160, 0);
  hipLaunchKernelGGL(fc_kernel, dim3(16, 8), dim3(256), 0, stream,
                     d1, dec_w2, dec_b2, d2, 1024, 512, 0);
  hipLaunchKernelGGL(fc_kernel, dim3(13, 8), dim3(256), 0, stream,
                     d2, dec_w3, dec_b3, out + 5120, 784, 1024, 1);
}

// Round 3
// 1043.887 us; speedup vs baseline: 10.1141x; 2.5195x over previous
//
#include <hip/hip_runtime.h>
#include <math.h>

// ============================================================================
// CapsuleNet forward, round 3.
// conv1 -> ht fp16 NHWC; wtrans; prim MFMA implicit GEMM (split-K 2);
// squash (reduce+bias) -> u[b,r,8] fp32;
// NEW: priors_kernel materializes P[c,b,r,16] in fp16 (188.7 MB) so routing
// no longer re-streams route_w per (c,b) block (was 3.35 GB -> ~0.45 GB);
// routing loads its contiguous 36.9 KB P slice into registers.
// ws layout: [ht|wtp|part] then P overlays them (all dead), u after P.
// ============================================================================

typedef _Float16 f16;
typedef _Float16 f16x8 __attribute__((ext_vector_type(8)));
typedef _Float16 f16x4 __attribute__((ext_vector_type(4)));
typedef float f32x4 __attribute__((ext_vector_type(4)));

__device__ __forceinline__ void gl_lds16(const void* g, void* l) {
  __builtin_amdgcn_global_load_lds(
      (const __attribute__((address_space(1))) void*)g,
      (__attribute__((address_space(3))) void*)l, 16, 0, 0);
}

// ---------------- conv1: x[512,1,28,28] -> ht fp16 NHWC [512,20,20,256] ----
__global__ __launch_bounds__(256, 2) void conv1_kernel(
    const float* __restrict__ x, const float* __restrict__ w,
    const float* __restrict__ bias, f16* __restrict__ ht)
{
  __shared__ float xs[784];
  const int b = blockIdx.x;
  const int t = threadIdx.x;          // t == output channel (ic of ht)
  for (int i = t; i < 784; i += 256) xs[i] = x[b * 784 + i];
  float wr[81];
#pragma unroll
  for (int k = 0; k < 81; ++k) wr[k] = w[t * 81 + k];
  const float bv = bias[t];
  __syncthreads();
  for (int oy = 0; oy < 20; ++oy) {
    float acc[20];
#pragma unroll
    for (int i = 0; i < 20; ++i) acc[i] = bv;
#pragma unroll
    for (int ky = 0; ky < 9; ++ky) {
      float xr[28];
#pragma unroll
      for (int q = 0; q < 7; ++q) {
        const float4 v = *(const float4*)&xs[(oy + ky) * 28 + q * 4];
        xr[q*4+0] = v.x; xr[q*4+1] = v.y; xr[q*4+2] = v.z; xr[q*4+3] = v.w;
      }
#pragma unroll
      for (int kx = 0; kx < 9; ++kx) {
        const float wv = wr[ky * 9 + kx];
#pragma unroll
        for (int ox = 0; ox < 20; ++ox) acc[ox] = fmaf(xr[ox + kx], wv, acc[ox]);
      }
    }
    f16* hp = &ht[(size_t)((b * 20 + oy) * 20) * 256 + t];
#pragma unroll
    for (int ox = 0; ox < 20; ++ox)
      hp[ox * 256] = (f16)fmaxf(acc[ox], 0.f);
  }
}

// --------- weight transpose: prim_w fp32 [oc][ic][kykx] -> wt fp16 [oc][kykx][ic]
__global__ void wtrans_kernel(const float* __restrict__ w, f16* __restrict__ wt)
{
  const int tid = blockIdx.x * 256 + threadIdx.x;   // ((oc*81+kykx)<<8)|ic
  const int ic = tid & 255;
  const int rest = tid >> 8;                        // oc*81 + kykx
  const int oc = rest / 81;
  const int kykx = rest - oc * 81;
  wt[tid] = (f16)w[oc * 20736 + ic * 81 + kykx];
}

// ---------------- primary caps conv: MFMA implicit GEMM --------------------
__global__ __launch_bounds__(256) void prim_mfma_kernel(
    const f16* __restrict__ ht, const f16* __restrict__ wt,
    float* __restrict__ part)
{
  __shared__ f16 smem[8192];           // As[128][32] | Bs[128][32], 16 KB
  f16* As = smem;
  f16* Bs = smem + 4096;
  const int t = threadIdx.x;
  const int wv = t >> 6, lane = t & 63;
  const int id = blockIdx.x;
  const int g = id >> 3;
  const int mb = (id & 7) + 8 * (g >> 2);
  const int nb = (g >> 1) & 1;
  const int ks = g & 1;
  const int m0 = mb * 128, n0 = nb * 128;

  long aoff[2], boff[2];
#pragma unroll
  for (int i = 0; i < 2; ++i) {
    const int c = wv * 128 + i * 64 + lane;
    const int r = c >> 2, o16 = c & 3;
    const int m = m0 + r;
    const int b = m / 36, pos = m - b * 36;
    const int oy = pos / 6, ox = pos - oy * 6;
    aoff[i] = (long)(((b * 20 + 2 * oy) * 20 + 2 * ox) * 256) * 2 + o16 * 16;
    const int oc = n0 + r;
    boff[i] = (long)oc * 41472 + o16 * 16;   // oc*81*256*2
  }
  char* As0 = (char*)As + wv * 2048;
  char* Bs0 = (char*)Bs + wv * 2048;
  const char* htc = (const char*)ht;
  const char* wtc = (const char*)wt;

  const int lrow = lane & 15, quad = lane >> 4;
  const int wm = wv & 1, wn = wv >> 1;
  f32x4 acc[4][4] = {};

  for (int s = ks * 324, e = ks * 324 + 324; s < e; ++s) {
    const int kykx = s >> 3, icb = s & 7;
    const int ky = kykx / 9, kx = kykx - ky * 9;
    const long astep = (long)(((ky * 20 + kx) * 256 + icb * 32) * 2);
    const long bstep = (long)((kykx * 256 + icb * 32) * 2);
    __syncthreads();
    gl_lds16(htc + aoff[0] + astep, As0);
    gl_lds16(htc + aoff[1] + astep, As0 + 1024);
    gl_lds16(wtc + boff[0] + bstep, Bs0);
    gl_lds16(wtc + boff[1] + bstep, Bs0 + 1024);
    __syncthreads();
    f16x8 af[4], bf[4];
#pragma unroll
    for (int mt = 0; mt < 4; ++mt)
      af[mt] = *(const f16x8*)&As[(wm * 64 + mt * 16 + lrow) * 32 + quad * 8];
#pragma unroll
    for (int nt = 0; nt < 4; ++nt)
      bf[nt] = *(const f16x8*)&Bs[(wn * 64 + nt * 16 + lrow) * 32 + quad * 8];
#pragma unroll
    for (int mt = 0; mt < 4; ++mt)
#pragma unroll
      for (int nt = 0; nt < 4; ++nt)
        acc[mt][nt] = __builtin_amdgcn_mfma_f32_16x16x32_f16(
            af[mt], bf[nt], acc[mt][nt], 0, 0, 0);
  }

  float* pp = part + (size_t)ks * 4718592;
#pragma unroll
  for (int mt = 0; mt < 4; ++mt) {
    const int mbase = m0 + wm * 64 + mt * 16 + quad * 4;
#pragma unroll
    for (int nt = 0; nt < 4; ++nt) {
      const int n = n0 + wn * 64 + nt * 16 + lrow;
#pragma unroll
      for (int rg = 0; rg < 4; ++rg)
        pp[(size_t)(mbase + rg) * 256 + n] = acc[mt][nt][rg];
    }
  }
}

// --------- split-K reduce + bias + squash -> u[512,1152,8] fp32 ------------
__global__ void squash_kernel(const float* __restrict__ part,
                              const float* __restrict__ bias,
                              float* __restrict__ u)
{
  const int tid = blockIdx.x * 256 + threadIdx.x;   // b*1152 + r
  if (tid >= 512 * 1152) return;
  const int b = tid / 1152;
  const int r = tid - b * 1152;
  const int cc = r / 36;
  const int pos = r - cc * 36;
  const float* p0 = part + (size_t)(b * 36 + pos) * 256;
  const float* p1 = p0 + 4718592;
  float v[8];
  float sq = 0.f;
#pragma unroll
  for (int i = 0; i < 8; ++i) {
    const int oc = i * 32 + cc;
    const float val = p0[oc] + p1[oc] + bias[oc];
    v[i] = val;
    sq = fmaf(val, val, sq);
  }
  const float scale = sq / ((1.f + sq) * sqrtf(sq));
  float* up = &u[(size_t)tid * 8];
#pragma unroll
  for (int i = 0; i < 8; ++i) up[i] = v[i] * scale;
}

// --------- priors: P[c,b,r,16] fp16 = einsum('bri,crio') -------------------
// grid (72 r-chunks, 8 b-chunks), 256 thr. lane = b_sub*4 + oq.
__global__ __launch_bounds__(256, 4) void priors_kernel(
    const float* __restrict__ u, const float* __restrict__ rw,
    f16* __restrict__ P)
{
  const int t = threadIdx.x;
  const int wv = t >> 6, lane = t & 63;
  const int b_sub = lane >> 2, oq = lane & 3;
  const int r0 = blockIdx.x * 16;
  const int b = blockIdx.y * 64 + wv * 16 + b_sub;
  for (int ri = 0; ri < 16; ++ri) {
    const int r = r0 + ri;
    const float4 ua = *(const float4*)&u[(size_t)(b * 1152 + r) * 8];
    const float4 ub = *(const float4*)&u[(size_t)(b * 1152 + r) * 8 + 4];
    const float uu[8] = {ua.x, ua.y, ua.z, ua.w, ub.x, ub.y, ub.z, ub.w};
    for (int c = 0; c < 10; ++c) {
      const float4* wp =
          (const float4*)&rw[(size_t)((c * 1152 + r) * 8) * 16 + oq * 4];
      float ax = 0.f, ay = 0.f, az = 0.f, aw = 0.f;
#pragma unroll
      for (int i = 0; i < 8; ++i) {
        const float4 w4 = wp[i * 4];          // +16 floats per i
        ax = fmaf(uu[i], w4.x, ax);
        ay = fmaf(uu[i], w4.y, ay);
        az = fmaf(uu[i], w4.z, az);
        aw = fmaf(uu[i], w4.w, aw);
      }
      f16x4 st;
      st[0] = (f16)ax; st[1] = (f16)ay; st[2] = (f16)az; st[3] = (f16)aw;
      *(f16x4*)&P[(size_t)((c * 512 + b) * 1152 + r) * 16 + oq * 4] = st;
    }
  }
}

// ---------------- dynamic routing, one block per (c,b) ---------------------
__device__ __forceinline__ float wave_sum(float v) {
#pragma unroll
  for (int off = 32; off > 0; off >>= 1) v += __shfl_xor(v, off);
  return v;
}
__device__ __forceinline__ float wave_max(float v) {
#pragma unroll
  for (int off = 32; off > 0; off >>= 1) v = fmaxf(v, __shfl_xor(v, off));
  return v;
}

__global__ __launch_bounds__(256, 2) void routing_kernel(
    const f16* __restrict__ Pg, float* __restrict__ caps)
{
  const int c = blockIdx.x >> 9;
  const int b = blockIdx.x & 511;
  const int t = threadIdx.x;
  const int wid = t >> 6;
  const int lane = t & 63;
  __shared__ float xred[4 * 17];

  float P[5][16];
  float lg[5];
  const int nk = (t < 128) ? 5 : 4;
#pragma unroll
  for (int k = 0; k < 5; ++k)
#pragma unroll
    for (int o = 0; o < 16; ++o) P[k][o] = 0.f;

  const f16* pbase = Pg + (size_t)((c * 512 + b) * 1152) * 16;
#pragma unroll
  for (int k = 0; k < 5; ++k) {
    if (k < nk) {
      const int r = t + (k << 8);
      const f16x8 p0 = *(const f16x8*)&pbase[(size_t)r * 16];
      const f16x8 p1 = *(const f16x8*)&pbase[(size_t)r * 16 + 8];
#pragma unroll
      for (int o = 0; o < 8; ++o) {
        P[k][o]     = (float)p0[o];
        P[k][o + 8] = (float)p1[o];
      }
    }
  }

  float v[16];
  {
    float sq = 0.f;
#pragma unroll
    for (int o = 0; o < 16; ++o) {
      float p = 0.f;
#pragma unroll
      for (int k = 0; k < 5; ++k) p += P[k][o];
      p = wave_sum(p);
      if (lane == 0) xred[wid * 17 + o] = p;
      v[o] = 0.f;
    }
    __syncthreads();
#pragma unroll
    for (int o = 0; o < 16; ++o) {
      const float s = (xred[o] + xred[17 + o] + xred[34 + o] + xred[51 + o]) *
                      (1.f / 1152.f);
      v[o] = s;
      sq = fmaf(s, s, sq);
    }
    const float scale = sq / ((1.f + sq) * sqrtf(sq));
#pragma unroll
    for (int o = 0; o < 16; ++o) v[o] *= scale;
    __syncthreads();
  }
#pragma unroll
  for (int k = 0; k < 5; ++k) {
    float a = 0.f;
#pragma unroll
    for (int o = 0; o < 16; ++o) a = fmaf(P[k][o], v[o], a);
    lg[k] = a;
  }

  for (int it = 1; it < 3; ++it) {
    float m = -1e30f;
#pragma unroll
    for (int k = 0; k < 5; ++k) if (k < nk) m = fmaxf(m, lg[k]);
    m = wave_max(m);
    if (lane == 0) xred[wid * 17 + 16] = m;
    __syncthreads();
    const float mx = fmaxf(fmaxf(xred[16], xred[17 + 16]),
                           fmaxf(xred[34 + 16], xred[51 + 16]));
    __syncthreads();
    float e[5];
#pragma unroll
    for (int k = 0; k < 5; ++k) e[k] = (k < nk) ? expf(lg[k] - mx) : 0.f;
    float pS = 0.f;
#pragma unroll
    for (int k = 0; k < 5; ++k) pS += e[k];
    pS = wave_sum(pS);
    if (lane == 0) xred[wid * 17 + 16] = pS;
#pragma unroll
    for (int o = 0; o < 16; ++o) {
      float p = 0.f;
#pragma unroll
      for (int k = 0; k < 5; ++k) p = fmaf(e[k], P[k][o], p);
      p = wave_sum(p);
      if (lane == 0) xred[wid * 17 + o] = p;
    }
    __syncthreads();
    const float S = xred[16] + xred[17 + 16] + xred[34 + 16] + xred[51 + 16];
    const float inv = 1.f / S;
    float sq = 0.f;
#pragma unroll
    for (int o = 0; o < 16; ++o) {
      const float s = (xred[o] + xred[17 + o] + xred[34 + o] + xred[51 + o]) * inv;
      v[o] = s;
      sq = fmaf(s, s, sq);
    }
    const float scale = sq / ((1.f + sq) * sqrtf(sq));
#pragma unroll
    for (int o = 0; o < 16; ++o) v[o] *= scale;
    __syncthreads();
    if (it < 2) {
#pragma unroll
      for (int k = 0; k < 5; ++k) {
        float a = 0.f;
#pragma unroll
        for (int o = 0; o < 16; ++o) a = fmaf(P[k][o], v[o], a);
        lg[k] += a;
      }
    }
  }
  if (t == 0) {
    float* cp = &caps[(b * 10 + c) * 16];
#pragma unroll
    for (int o = 0; o < 16; ++o) cp[o] = v[o];
  }
}

// --------- classes softmax + argmax one-hot mask ---------------------------
__global__ void classes_kernel(const float* __restrict__ caps,
                               float* __restrict__ out_classes,
                               float* __restrict__ d0)
{
  const int b = blockIdx.x * 256 + threadIdx.x;
  if (b >= 512) return;
  float nrm[10];
#pragma unroll
  for (int cc = 0; cc < 10; ++cc) {
    float sq = 0.f;
#pragma unroll
    for (int o = 0; o < 16; ++o) {
      const float vv = caps[(b * 10 + cc) * 16 + o];
      sq = fmaf(vv, vv, sq);
    }
    nrm[cc] = sqrtf(sq);
  }
  float mx = nrm[0]; int cs = 0;
#pragma unroll
  for (int cc = 1; cc < 10; ++cc)
    if (nrm[cc] > mx) { mx = nrm[cc]; cs = cc; }
  float e[10], ssum = 0.f;
#pragma unroll
  for (int cc = 0; cc < 10; ++cc) { e[cc] = expf(nrm[cc] - mx); ssum += e[cc]; }
  const float inv = 1.f / ssum;
#pragma unroll
  for (int cc = 0; cc < 10; ++cc) out_classes[b * 10 + cc] = e[cc] * inv;
#pragma unroll
  for (int cc = 0; cc < 10; ++cc)
#pragma unroll
    for (int o = 0; o < 16; ++o)
      d0[b * 160 + cc * 16 + o] = (cc == cs) ? caps[(b * 10 + cc) * 16 + o] : 0.f;
}

// --------- decoder GEMM: C[M,N] = act(A[M,K] @ W[N,K]^T + bias) ------------
__global__ __launch_bounds__(256, 2) void fc_kernel(
    const float* __restrict__ A, const float* __restrict__ W,
    const float* __restrict__ bias, float* __restrict__ C,
    int N, int K, int act)
{
  __shared__ float As[64][17];
  __shared__ float Ws[64][17];
  const int t = threadIdx.x;
  const int tm = t >> 4, tn = t & 15;
  const int m0 = blockIdx.y << 6, n0 = blockIdx.x << 6;
  const int lr = t >> 2, lq = (t & 3) << 2;
  float acc[4][4] = {};
  for (int k0 = 0; k0 < K; k0 += 16) {
    const float4 av = *(const float4*)&A[(m0 + lr) * K + k0 + lq];
    float4 wv = make_float4(0.f, 0.f, 0.f, 0.f);
    const int wn = n0 + lr;
    if (wn < N) wv = *(const float4*)&W[wn * K + k0 + lq];
    __syncthreads();
    As[lr][lq+0] = av.x; As[lr][lq+1] = av.y; As[lr][lq+2] = av.z; As[lr][lq+3] = av.w;
    Ws[lr][lq+0] = wv.x; Ws[lr][lq+1] = wv.y; Ws[lr][lq+2] = wv.z; Ws[lr][lq+3] = wv.w;
    __syncthreads();
#pragma unroll
    for (int kk = 0; kk < 16; ++kk) {
      float a[4], w[4];
#pragma unroll
      for (int i = 0; i < 4; ++i) a[i] = As[tm * 4 + i][kk];
#pragma unroll
      for (int j = 0; j < 4; ++j) w[j] = Ws[tn * 4 + j][kk];
#pragma unroll
      for (int i = 0; i < 4; ++i)
#pragma unroll
        for (int j = 0; j < 4; ++j) acc[i][j] = fmaf(a[i], w[j], acc[i][j]);
    }
  }
#pragma unroll
  for (int i = 0; i < 4; ++i) {
    const int m = m0 + tm * 4 + i;
#pragma unroll
    for (int j = 0; j < 4; ++j) {
      const int n = n0 + tn * 4 + j;
      if (n < N) {
        float vv = acc[i][j] + bias[n];
        vv = act ? (1.f / (1.f + expf(-vv))) : fmaxf(vv, 0.f);
        C[m * N + n] = vv;
      }
    }
  }
}

// ============================================================================
extern "C" void kernel_launch(void* const* d_in, const int* in_sizes, int n_in,
                              void* d_out, int out_size, void* d_ws, size_t ws_size,
                              hipStream_t stream)
{
  const float* x       = (const float*)d_in[0];
  const float* conv1_w = (const float*)d_in[1];
  const float* conv1_b = (const float*)d_in[2];
  const float* prim_w  = (const float*)d_in[3];
  const float* prim_b  = (const float*)d_in[4];
  const float* route_w = (const float*)d_in[5];
  const float* dec_w1  = (const float*)d_in[6];
  const float* dec_b1  = (const float*)d_in[7];
  const float* dec_w2  = (const float*)d_in[8];
  const float* dec_b2  = (const float*)d_in[9];
  const float* dec_w3  = (const float*)d_in[10];
  const float* dec_b3  = (const float*)d_in[11];
  float* out = (float*)d_out;

  char* ws = (char*)d_ws;
  // Phase 1 (conv/prim): ht 0..104.86M, wtp ..115.47M, part ..153.22M
  f16*   ht   = (f16*)(ws);
  f16*   wtp  = (f16*)(ws + 104857600);
  float* part = (float*)(ws + 115474432);
  // u lives beyond the P region (P overlays dead ht/wtp/part).
  float* u    = (float*)(ws + 188743680);          // 18,874,368 B
  f16*   P    = (f16*)(ws);                        // 188,743,680 B
  float* caps = (float*)(ws + 207618048);          // 327,680 B
  float* d0   = (float*)(ws + 207945728);          // 327,680 B
  float* d1   = (float*)(ws + 208273408);          // 1,048,576 B
  float* d2   = (float*)(ws + 209321984);          // 2,097,152 B

  hipLaunchKernelGGL(conv1_kernel, dim3(512), dim3(256), 0, stream,
                     x, conv1_w, conv1_b, ht);
  hipLaunchKernelGGL(wtrans_kernel, dim3(20736), dim3(256), 0, stream,
                     prim_w, wtp);
  hipLaunchKernelGGL(prim_mfma_kernel, dim3(576), dim3(256), 0, stream,
                     ht, wtp, part);
  hipLaunchKernelGGL(squash_kernel, dim3(2304), dim3(256), 0, stream,
                     part, prim_b, u);
  hipLaunchKernelGGL(priors_kernel, dim3(72, 8), dim3(256), 0, stream,
                     u, route_w, P);
  hipLaunchKernelGGL(routing_kernel, dim3(5120), dim3(256), 0, stream,
                     P, caps);
  hipLaunchKernelGGL(classes_kernel, dim3(2), dim3(256), 0, stream,
                     caps, out, d0);
  hipLaunchKernelGGL(fc_kernel, dim3(8, 8), dim3(256), 0, stream,
                     d0, dec_w1, dec_b1, d1, 512, 160, 0);
  hipLaunchKernelGGL(fc_kernel, dim3(16, 8), dim3(256), 0, stream,
                     d1, dec_w2, dec_b2, d2, 1024, 512, 0);
  hipLaunchKernelGGL(fc_kernel, dim3(13, 8), dim3(256), 0, stream,
                     d2, dec_w3, dec_b3, out + 5120, 784, 1024, 1);
}